// Round 11
// baseline (54.033 us; speedup 1.0000x reference)
//
#include <hip/hip_runtime.h>

#define IN_DIM  4096
#define OUT_DIM 8192
#define BATCH   4096
#define ROWS    4          // rows staged per block, interleaved per-column (b128 gather)
#define TPB     512
#define CPT     8          // columns per thread per chunk -> 8 back-to-back nt stores
#define NCHUNK  (OUT_DIM / (TPB * CPT))   // 2
#define CSTRIDE (TPB * CPT)               // 4096 columns per chunk

typedef float f32x4 __attribute__((ext_vector_type(4)));

// swizzled LDS byte address of the 4-row group for column c (bijective involution
// within the 64 KB tile); applied on BOTH the staging write and the gather read.
__device__ __forceinline__ uint32_t swz(uint32_t c) {
    return (c ^ ((c >> 3) & 7u)) << 4;   // max 65520 -> fits u16
}

// difflogic op-coefficient table: op_i(a,b) = T[i][0] + T[i][1]*a + T[i][2]*b + T[i][3]*ab
__device__ __constant__ float c_T[16][4] = {
    {0.f,  0.f,  0.f,  0.f},
    {0.f,  0.f,  0.f,  1.f},
    {0.f,  1.f,  0.f, -1.f},
    {0.f,  1.f,  0.f,  0.f},
    {0.f,  0.f,  1.f, -1.f},
    {0.f,  0.f,  1.f,  0.f},
    {0.f,  1.f,  1.f, -2.f},
    {0.f,  1.f,  1.f, -1.f},
    {1.f, -1.f, -1.f,  1.f},
    {1.f, -1.f, -1.f,  2.f},
    {1.f,  0.f, -1.f,  0.f},
    {1.f,  0.f, -1.f,  1.f},
    {1.f, -1.f,  0.f,  0.f},
    {1.f, -1.f,  0.f,  1.f},
    {1.f,  0.f,  0.f, -1.f},
    {1.f,  0.f,  0.f,  0.f},
};

// Per column j: coeff[j] = softmax(weight[j,:]) @ T, and spk[j] = packed
// pre-swizzled LDS byte offsets of the two gather operands (u16|u16).
__global__ __launch_bounds__(256) void prep_kernel(const float* __restrict__ w,
                                                   const int* __restrict__ idx,
                                                   float4* __restrict__ coeff,
                                                   uint32_t* __restrict__ spk) {
    int j = blockIdx.x * blockDim.x + threadIdx.x;
    if (j >= OUT_DIM) return;
    const float4* wp = (const float4*)(w + (size_t)j * 16);
    float4 a0 = wp[0], a1 = wp[1], a2 = wp[2], a3 = wp[3];
    float v[16] = {a0.x, a0.y, a0.z, a0.w, a1.x, a1.y, a1.z, a1.w,
                   a2.x, a2.y, a2.z, a2.w, a3.x, a3.y, a3.z, a3.w};
    float m = v[0];
#pragma unroll
    for (int i = 1; i < 16; ++i) m = fmaxf(m, v[i]);
    float s = 0.f, c0 = 0.f, c1 = 0.f, c2 = 0.f, c3 = 0.f;
#pragma unroll
    for (int i = 0; i < 16; ++i) {
        float e = __expf(v[i] - m);
        s += e;
        c0 += e * c_T[i][0];
        c1 += e * c_T[i][1];
        c2 += e * c_T[i][2];
        c3 += e * c_T[i][3];
    }
    float inv = 1.f / s;
    coeff[j] = make_float4(c0 * inv, c1 * inv, c2 * inv, c3 * inv);
    spk[j] = swz((uint32_t)idx[j]) | (swz((uint32_t)idx[OUT_DIM + j]) << 16);
}

// R6 skeleton with CPT=8: per chunk, 16 b128 gathers then 8 back-to-back
// nontemporal b128 stores (longer uninterrupted store bursts, 2 chunks total).
__global__ __launch_bounds__(TPB, 4) void logic_main(const float* __restrict__ x,
                                                     const uint32_t* __restrict__ spk,
                                                     const float4* __restrict__ coeff,
                                                     float* __restrict__ out) {
    __shared__ float xs[ROWS * IN_DIM];  // 64 KB, swizzled 4-row column groups
    const char* lds = (const char*)xs;

    const int row0 = blockIdx.x * ROWS;
    const int jbase = threadIdx.x * CPT;

    // --- prefetch chunk 0's metadata (overlaps with staging) ---
    uint4  Plo = *(const uint4*)(spk + jbase);
    uint4  Phi = *(const uint4*)(spk + jbase + 4);
    float4 cf[CPT];
#pragma unroll
    for (int q = 0; q < CPT; ++q) cf[q] = coeff[jbase + q];

    // --- stage 4 rows, transposing to interleaved+swizzled layout ---
    {
        const float4* rp = (const float4*)(x + (size_t)row0 * IN_DIM);
#pragma unroll
        for (int it = 0; it < IN_DIM / 4 / TPB; ++it) {  // 2 iters
            const int t = it * TPB + threadIdx.x;        // col-group (4 cols)
            float4 r0 = rp[t];
            float4 r1 = rp[t + IN_DIM / 4];
            float4 r2 = rp[t + 2 * IN_DIM / 4];
            float4 r3 = rp[t + 3 * IN_DIM / 4];
            const float* p0 = &r0.x; const float* p1 = &r1.x;
            const float* p2 = &r2.x; const float* p3 = &r3.x;
#pragma unroll
            for (int k = 0; k < 4; ++k) {
                f32x4 v; v.x = p0[k]; v.y = p1[k]; v.z = p2[k]; v.w = p3[k];
                *(f32x4*)((char*)xs + swz(4u * (uint32_t)t + k)) = v;
            }
        }
    }
    __syncthreads();

#pragma unroll
    for (int chunk = 0; chunk < NCHUNK; ++chunk) {
        const int j = chunk * CSTRIDE + jbase;
        const uint4 IPlo = Plo, IPhi = Phi;
        float4 C[CPT];
#pragma unroll
        for (int q = 0; q < CPT; ++q) C[q] = cf[q];
        if (chunk < NCHUNK - 1) {
            const int jn = j + CSTRIDE;
            Plo = *(const uint4*)(spk + jn);
            Phi = *(const uint4*)(spk + jn + 4);
#pragma unroll
            for (int q = 0; q < CPT; ++q) cf[q] = coeff[jn + q];
        }
        // gathers: one b128 per (col, a/b) serves all 4 rows; offsets pre-swizzled
        f32x4 A[CPT], B[CPT];
        A[0] = *(const f32x4*)(lds + (IPlo.x & 0xFFFFu));
        B[0] = *(const f32x4*)(lds + (IPlo.x >> 16));
        A[1] = *(const f32x4*)(lds + (IPlo.y & 0xFFFFu));
        B[1] = *(const f32x4*)(lds + (IPlo.y >> 16));
        A[2] = *(const f32x4*)(lds + (IPlo.z & 0xFFFFu));
        B[2] = *(const f32x4*)(lds + (IPlo.z >> 16));
        A[3] = *(const f32x4*)(lds + (IPlo.w & 0xFFFFu));
        B[3] = *(const f32x4*)(lds + (IPlo.w >> 16));
        A[4] = *(const f32x4*)(lds + (IPhi.x & 0xFFFFu));
        B[4] = *(const f32x4*)(lds + (IPhi.x >> 16));
        A[5] = *(const f32x4*)(lds + (IPhi.y & 0xFFFFu));
        B[5] = *(const f32x4*)(lds + (IPhi.y >> 16));
        A[6] = *(const f32x4*)(lds + (IPhi.z & 0xFFFFu));
        B[6] = *(const f32x4*)(lds + (IPhi.z >> 16));
        A[7] = *(const f32x4*)(lds + (IPhi.w & 0xFFFFu));
        B[7] = *(const f32x4*)(lds + (IPhi.w >> 16));

        // o[r][h] = cols j+4h .. j+4h+3 of row row0+r
#define POLY(C, a, b) ((C).x + (C).y * (a) + (C).z * (b) + (C).w * ((a) * (b)))
        f32x4 o[ROWS][2];
#pragma unroll
        for (int h = 0; h < 2; ++h) {
#pragma unroll
            for (int q = 0; q < 4; ++q) {
                const int g = 4 * h + q;
#pragma unroll
                for (int r = 0; r < ROWS; ++r)
                    o[r][h][q] = POLY(C[g], A[g][r], B[g][r]);
            }
        }
#undef POLY
        // 8 back-to-back nontemporal b128 stores
#pragma unroll
        for (int r = 0; r < ROWS; ++r) {
            float* orow = out + (size_t)(row0 + r) * OUT_DIM + j;
            __builtin_nontemporal_store(o[r][0], (f32x4*)orow);
            __builtin_nontemporal_store(o[r][1], (f32x4*)(orow + 4));
        }
    }
}

extern "C" void kernel_launch(void* const* d_in, const int* in_sizes, int n_in,
                              void* d_out, int out_size, void* d_ws, size_t ws_size,
                              hipStream_t stream) {
    const float* x   = (const float*)d_in[0];
    const int*   idx = (const int*)d_in[1];     // (2, OUT_DIM) int32
    const float* w   = (const float*)d_in[2];   // (OUT_DIM, 16)
    float* out = (float*)d_out;
    float4*   coeff = (float4*)d_ws;                                        // 128 KB
    uint32_t* spk   = (uint32_t*)((char*)d_ws + OUT_DIM * sizeof(float4));  // 32 KB

    prep_kernel<<<OUT_DIM / 256, 256, 0, stream>>>(w, idx, coeff, spk);
    logic_main<<<BATCH / ROWS, TPB, 0, stream>>>(x, spk, coeff, out);
}

// Round 12
// 41.032 us; speedup vs baseline: 1.3168x; 1.3168x over previous
//
#include <hip/hip_runtime.h>

#define IN_DIM  4096
#define OUT_DIM 8192
#define BATCH   4096
#define ROWS    4          // rows staged per block, interleaved per-column (b128 gather)
#define TPB     512
#define CPT     4          // columns per thread per chunk
#define NCHUNK  (OUT_DIM / (TPB * CPT))   // 4
#define CSTRIDE (TPB * CPT)               // 2048 columns per chunk

typedef float f32x4 __attribute__((ext_vector_type(4)));

// swizzled LDS byte address of the 4-row group for column c (bijective involution
// within the 64 KB tile); applied on BOTH the staging write and the gather read.
__device__ __forceinline__ uint32_t swz(uint32_t c) {
    return (c ^ ((c >> 3) & 7u)) << 4;   // max 65520 -> fits u16
}

// difflogic op-coefficient table: op_i(a,b) = T[i][0] + T[i][1]*a + T[i][2]*b + T[i][3]*ab
__device__ __constant__ float c_T[16][4] = {
    {0.f,  0.f,  0.f,  0.f},
    {0.f,  0.f,  0.f,  1.f},
    {0.f,  1.f,  0.f, -1.f},
    {0.f,  1.f,  0.f,  0.f},
    {0.f,  0.f,  1.f, -1.f},
    {0.f,  0.f,  1.f,  0.f},
    {0.f,  1.f,  1.f, -2.f},
    {0.f,  1.f,  1.f, -1.f},
    {1.f, -1.f, -1.f,  1.f},
    {1.f, -1.f, -1.f,  2.f},
    {1.f,  0.f, -1.f,  0.f},
    {1.f,  0.f, -1.f,  1.f},
    {1.f, -1.f,  0.f,  0.f},
    {1.f, -1.f,  0.f,  1.f},
    {1.f,  0.f,  0.f, -1.f},
    {1.f,  0.f,  0.f,  0.f},
};

// Per column j: coeff[j] = softmax(weight[j,:]) @ T, and spk[j] = packed
// pre-swizzled LDS byte offsets of the two gather operands (u16|u16).
__global__ __launch_bounds__(256) void prep_kernel(const float* __restrict__ w,
                                                   const int* __restrict__ idx,
                                                   float4* __restrict__ coeff,
                                                   uint32_t* __restrict__ spk) {
    int j = blockIdx.x * blockDim.x + threadIdx.x;
    if (j >= OUT_DIM) return;
    const float4* wp = (const float4*)(w + (size_t)j * 16);
    float4 a0 = wp[0], a1 = wp[1], a2 = wp[2], a3 = wp[3];
    float v[16] = {a0.x, a0.y, a0.z, a0.w, a1.x, a1.y, a1.z, a1.w,
                   a2.x, a2.y, a2.z, a2.w, a3.x, a3.y, a3.z, a3.w};
    float m = v[0];
#pragma unroll
    for (int i = 1; i < 16; ++i) m = fmaxf(m, v[i]);
    float s = 0.f, c0 = 0.f, c1 = 0.f, c2 = 0.f, c3 = 0.f;
#pragma unroll
    for (int i = 0; i < 16; ++i) {
        float e = __expf(v[i] - m);
        s += e;
        c0 += e * c_T[i][0];
        c1 += e * c_T[i][1];
        c2 += e * c_T[i][2];
        c3 += e * c_T[i][3];
    }
    float inv = 1.f / s;
    coeff[j] = make_float4(c0 * inv, c1 * inv, c2 * inv, c3 * inv);
    spk[j] = swz((uint32_t)idx[j]) | (swz((uint32_t)idx[OUT_DIM + j]) << 16);
}

// R6 skeleton, single change: PLAIN (L2 write-back) stores instead of
// nontemporal — isolating the store-path A/B that R4 bundled.
__global__ __launch_bounds__(TPB, 4) void logic_main(const float* __restrict__ x,
                                                     const uint32_t* __restrict__ spk,
                                                     const float4* __restrict__ coeff,
                                                     float* __restrict__ out) {
    __shared__ float xs[ROWS * IN_DIM];  // 64 KB, swizzled 4-row column groups
    const char* lds = (const char*)xs;

    const int row0 = blockIdx.x * ROWS;
    const int jbase = threadIdx.x * CPT;

    // --- prefetch chunk 0's metadata (overlaps with staging) ---
    uint4  P = *(const uint4*)(spk + jbase);
    float4 c0 = coeff[jbase + 0];
    float4 c1 = coeff[jbase + 1];
    float4 c2 = coeff[jbase + 2];
    float4 c3 = coeff[jbase + 3];

    // --- stage 4 rows, transposing to interleaved+swizzled layout ---
    {
        const float4* rp = (const float4*)(x + (size_t)row0 * IN_DIM);
#pragma unroll
        for (int it = 0; it < IN_DIM / 4 / TPB; ++it) {  // 2 iters
            const int t = it * TPB + threadIdx.x;        // col-group (4 cols)
            float4 r0 = rp[t];
            float4 r1 = rp[t + IN_DIM / 4];
            float4 r2 = rp[t + 2 * IN_DIM / 4];
            float4 r3 = rp[t + 3 * IN_DIM / 4];
            const float* p0 = &r0.x; const float* p1 = &r1.x;
            const float* p2 = &r2.x; const float* p3 = &r3.x;
#pragma unroll
            for (int k = 0; k < 4; ++k) {
                f32x4 v; v.x = p0[k]; v.y = p1[k]; v.z = p2[k]; v.w = p3[k];
                *(f32x4*)((char*)xs + swz(4u * (uint32_t)t + k)) = v;
            }
        }
    }
    __syncthreads();

#pragma unroll
    for (int chunk = 0; chunk < NCHUNK; ++chunk) {
        const int j = chunk * CSTRIDE + jbase;
        const uint4  IP = P;
        const float4 C0 = c0, C1 = c1, C2 = c2, C3 = c3;
        if (chunk < NCHUNK - 1) {
            const int jn = j + CSTRIDE;
            P  = *(const uint4*)(spk + jn);
            c0 = coeff[jn + 0];
            c1 = coeff[jn + 1];
            c2 = coeff[jn + 2];
            c3 = coeff[jn + 3];
        }
        // gathers: one b128 per (col, a/b) serves all 4 rows; offsets pre-swizzled
        const f32x4 A0 = *(const f32x4*)(lds + (IP.x & 0xFFFFu));
        const f32x4 B0 = *(const f32x4*)(lds + (IP.x >> 16));
        const f32x4 A1 = *(const f32x4*)(lds + (IP.y & 0xFFFFu));
        const f32x4 B1 = *(const f32x4*)(lds + (IP.y >> 16));
        const f32x4 A2 = *(const f32x4*)(lds + (IP.z & 0xFFFFu));
        const f32x4 B2 = *(const f32x4*)(lds + (IP.z >> 16));
        const f32x4 A3 = *(const f32x4*)(lds + (IP.w & 0xFFFFu));
        const f32x4 B3 = *(const f32x4*)(lds + (IP.w >> 16));

        f32x4 o0, o1, o2, o3;  // o[r] holds cols j..j+3 for row r
#define POLY(C, a, b) ((C).x + (C).y * (a) + (C).z * (b) + (C).w * ((a) * (b)))
        o0.x = POLY(C0, A0.x, B0.x); o1.x = POLY(C0, A0.y, B0.y);
        o2.x = POLY(C0, A0.z, B0.z); o3.x = POLY(C0, A0.w, B0.w);
        o0.y = POLY(C1, A1.x, B1.x); o1.y = POLY(C1, A1.y, B1.y);
        o2.y = POLY(C1, A1.z, B1.z); o3.y = POLY(C1, A1.w, B1.w);
        o0.z = POLY(C2, A2.x, B2.x); o1.z = POLY(C2, A2.y, B2.y);
        o2.z = POLY(C2, A2.z, B2.z); o3.z = POLY(C2, A2.w, B2.w);
        o0.w = POLY(C3, A3.x, B3.x); o1.w = POLY(C3, A3.y, B3.y);
        o2.w = POLY(C3, A3.z, B3.z); o3.w = POLY(C3, A3.w, B3.w);
#undef POLY

        *(f32x4*)(out + (size_t)(row0 + 0) * OUT_DIM + j) = o0;
        *(f32x4*)(out + (size_t)(row0 + 1) * OUT_DIM + j) = o1;
        *(f32x4*)(out + (size_t)(row0 + 2) * OUT_DIM + j) = o2;
        *(f32x4*)(out + (size_t)(row0 + 3) * OUT_DIM + j) = o3;
    }
}

extern "C" void kernel_launch(void* const* d_in, const int* in_sizes, int n_in,
                              void* d_out, int out_size, void* d_ws, size_t ws_size,
                              hipStream_t stream) {
    const float* x   = (const float*)d_in[0];
    const int*   idx = (const int*)d_in[1];     // (2, OUT_DIM) int32
    const float* w   = (const float*)d_in[2];   // (OUT_DIM, 16)
    float* out = (float*)d_out;
    float4*   coeff = (float4*)d_ws;                                        // 128 KB
    uint32_t* spk   = (uint32_t*)((char*)d_ws + OUT_DIM * sizeof(float4));  // 32 KB

    prep_kernel<<<OUT_DIM / 256, 256, 0, stream>>>(w, idx, coeff, spk);
    logic_main<<<BATCH / ROWS, TPB, 0, stream>>>(x, spk, coeff, out);
}

// Round 13
// 39.717 us; speedup vs baseline: 1.3604x; 1.0331x over previous
//
#include <hip/hip_runtime.h>

#define IN_DIM  4096
#define OUT_DIM 8192
#define BATCH   4096
#define ROWS    4          // rows staged per block, interleaved per-column (b128 gather)
#define TPB     512
#define CPT     4          // columns per thread per chunk
#define NCHUNK  (OUT_DIM / (TPB * CPT))   // 4
#define CSTRIDE (TPB * CPT)               // 2048 columns per chunk

typedef float f32x4 __attribute__((ext_vector_type(4)));

// swizzled LDS byte address of the 4-row group for column c (bijective involution
// within the 64 KB tile); applied on BOTH the staging write and the gather read.
__device__ __forceinline__ uint32_t swz(uint32_t c) {
    return (c ^ ((c >> 3) & 7u)) << 4;   // max 65520 -> fits u16
}

// difflogic op-coefficient table: op_i(a,b) = T[i][0] + T[i][1]*a + T[i][2]*b + T[i][3]*ab
__device__ __constant__ float c_T[16][4] = {
    {0.f,  0.f,  0.f,  0.f},
    {0.f,  0.f,  0.f,  1.f},
    {0.f,  1.f,  0.f, -1.f},
    {0.f,  1.f,  0.f,  0.f},
    {0.f,  0.f,  1.f, -1.f},
    {0.f,  0.f,  1.f,  0.f},
    {0.f,  1.f,  1.f, -2.f},
    {0.f,  1.f,  1.f, -1.f},
    {1.f, -1.f, -1.f,  1.f},
    {1.f, -1.f, -1.f,  2.f},
    {1.f,  0.f, -1.f,  0.f},
    {1.f,  0.f, -1.f,  1.f},
    {1.f, -1.f,  0.f,  0.f},
    {1.f, -1.f,  0.f,  1.f},
    {1.f,  0.f,  0.f, -1.f},
    {1.f,  0.f,  0.f,  0.f},
};

// Per column j: coeff[j] = softmax(weight[j,:]) @ T, and spk[j] = packed
// pre-swizzled LDS byte offsets of the two gather operands (u16|u16).
__global__ __launch_bounds__(256) void prep_kernel(const float* __restrict__ w,
                                                   const int* __restrict__ idx,
                                                   float4* __restrict__ coeff,
                                                   uint32_t* __restrict__ spk) {
    int j = blockIdx.x * blockDim.x + threadIdx.x;
    if (j >= OUT_DIM) return;
    const float4* wp = (const float4*)(w + (size_t)j * 16);
    float4 a0 = wp[0], a1 = wp[1], a2 = wp[2], a3 = wp[3];
    float v[16] = {a0.x, a0.y, a0.z, a0.w, a1.x, a1.y, a1.z, a1.w,
                   a2.x, a2.y, a2.z, a2.w, a3.x, a3.y, a3.z, a3.w};
    float m = v[0];
#pragma unroll
    for (int i = 1; i < 16; ++i) m = fmaxf(m, v[i]);
    float s = 0.f, c0 = 0.f, c1 = 0.f, c2 = 0.f, c3 = 0.f;
#pragma unroll
    for (int i = 0; i < 16; ++i) {
        float e = __expf(v[i] - m);
        s += e;
        c0 += e * c_T[i][0];
        c1 += e * c_T[i][1];
        c2 += e * c_T[i][2];
        c3 += e * c_T[i][3];
    }
    float inv = 1.f / s;
    coeff[j] = make_float4(c0 * inv, c1 * inv, c2 * inv, c3 * inv);
    spk[j] = swz((uint32_t)idx[j]) | (swz((uint32_t)idx[OUT_DIM + j]) << 16);
}

// Best-measured configuration (R6, 39.74 us): 4 rows staged in LDS as swizzled
// per-column 16 B groups (one ds_read_b128 serves 4 rows), metadata-only
// register prefetch one chunk ahead, unrolled 4-chunk sweep, nontemporal
// f32x4 stores. launch_bounds(512,4) clamps VGPR<=128 -> 2 blocks/CU.
__global__ __launch_bounds__(TPB, 4) void logic_main(const float* __restrict__ x,
                                                     const uint32_t* __restrict__ spk,
                                                     const float4* __restrict__ coeff,
                                                     float* __restrict__ out) {
    __shared__ float xs[ROWS * IN_DIM];  // 64 KB, swizzled 4-row column groups
    const char* lds = (const char*)xs;

    const int row0 = blockIdx.x * ROWS;
    const int jbase = threadIdx.x * CPT;

    // --- prefetch chunk 0's metadata (overlaps with staging) ---
    uint4  P = *(const uint4*)(spk + jbase);
    float4 c0 = coeff[jbase + 0];
    float4 c1 = coeff[jbase + 1];
    float4 c2 = coeff[jbase + 2];
    float4 c3 = coeff[jbase + 3];

    // --- stage 4 rows, transposing to interleaved+swizzled layout ---
    {
        const float4* rp = (const float4*)(x + (size_t)row0 * IN_DIM);
#pragma unroll
        for (int it = 0; it < IN_DIM / 4 / TPB; ++it) {  // 2 iters
            const int t = it * TPB + threadIdx.x;        // col-group (4 cols)
            float4 r0 = rp[t];
            float4 r1 = rp[t + IN_DIM / 4];
            float4 r2 = rp[t + 2 * IN_DIM / 4];
            float4 r3 = rp[t + 3 * IN_DIM / 4];
            const float* p0 = &r0.x; const float* p1 = &r1.x;
            const float* p2 = &r2.x; const float* p3 = &r3.x;
#pragma unroll
            for (int k = 0; k < 4; ++k) {
                f32x4 v; v.x = p0[k]; v.y = p1[k]; v.z = p2[k]; v.w = p3[k];
                *(f32x4*)((char*)xs + swz(4u * (uint32_t)t + k)) = v;
            }
        }
    }
    __syncthreads();

#pragma unroll
    for (int chunk = 0; chunk < NCHUNK; ++chunk) {
        const int j = chunk * CSTRIDE + jbase;
        const uint4  IP = P;
        const float4 C0 = c0, C1 = c1, C2 = c2, C3 = c3;
        if (chunk < NCHUNK - 1) {
            const int jn = j + CSTRIDE;
            P  = *(const uint4*)(spk + jn);
            c0 = coeff[jn + 0];
            c1 = coeff[jn + 1];
            c2 = coeff[jn + 2];
            c3 = coeff[jn + 3];
        }
        // gathers: one b128 per (col, a/b) serves all 4 rows; offsets pre-swizzled
        const f32x4 A0 = *(const f32x4*)(lds + (IP.x & 0xFFFFu));
        const f32x4 B0 = *(const f32x4*)(lds + (IP.x >> 16));
        const f32x4 A1 = *(const f32x4*)(lds + (IP.y & 0xFFFFu));
        const f32x4 B1 = *(const f32x4*)(lds + (IP.y >> 16));
        const f32x4 A2 = *(const f32x4*)(lds + (IP.z & 0xFFFFu));
        const f32x4 B2 = *(const f32x4*)(lds + (IP.z >> 16));
        const f32x4 A3 = *(const f32x4*)(lds + (IP.w & 0xFFFFu));
        const f32x4 B3 = *(const f32x4*)(lds + (IP.w >> 16));

        f32x4 o0, o1, o2, o3;  // o[r] holds cols j..j+3 for row r
#define POLY(C, a, b) ((C).x + (C).y * (a) + (C).z * (b) + (C).w * ((a) * (b)))
        o0.x = POLY(C0, A0.x, B0.x); o1.x = POLY(C0, A0.y, B0.y);
        o2.x = POLY(C0, A0.z, B0.z); o3.x = POLY(C0, A0.w, B0.w);
        o0.y = POLY(C1, A1.x, B1.x); o1.y = POLY(C1, A1.y, B1.y);
        o2.y = POLY(C1, A1.z, B1.z); o3.y = POLY(C1, A1.w, B1.w);
        o0.z = POLY(C2, A2.x, B2.x); o1.z = POLY(C2, A2.y, B2.y);
        o2.z = POLY(C2, A2.z, B2.z); o3.z = POLY(C2, A2.w, B2.w);
        o0.w = POLY(C3, A3.x, B3.x); o1.w = POLY(C3, A3.y, B3.y);
        o2.w = POLY(C3, A3.z, B3.z); o3.w = POLY(C3, A3.w, B3.w);
#undef POLY

        __builtin_nontemporal_store(o0, (f32x4*)(out + (size_t)(row0 + 0) * OUT_DIM + j));
        __builtin_nontemporal_store(o1, (f32x4*)(out + (size_t)(row0 + 1) * OUT_DIM + j));
        __builtin_nontemporal_store(o2, (f32x4*)(out + (size_t)(row0 + 2) * OUT_DIM + j));
        __builtin_nontemporal_store(o3, (f32x4*)(out + (size_t)(row0 + 3) * OUT_DIM + j));
    }
}

extern "C" void kernel_launch(void* const* d_in, const int* in_sizes, int n_in,
                              void* d_out, int out_size, void* d_ws, size_t ws_size,
                              hipStream_t stream) {
    const float* x   = (const float*)d_in[0];
    const int*   idx = (const int*)d_in[1];     // (2, OUT_DIM) int32
    const float* w   = (const float*)d_in[2];   // (OUT_DIM, 16)
    float* out = (float*)d_out;
    float4*   coeff = (float4*)d_ws;                                        // 128 KB
    uint32_t* spk   = (uint32_t*)((char*)d_ws + OUT_DIM * sizeof(float4));  // 32 KB

    prep_kernel<<<OUT_DIM / 256, 256, 0, stream>>>(w, idx, coeff, spk);
    logic_main<<<BATCH / ROWS, TPB, 0, stream>>>(x, spk, coeff, out);
}